// Round 2
// baseline (76.137 us; speedup 1.0000x reference)
//
#include <hip/hip_runtime.h>

// ProposalLayer: for each proposal (b,p), find nearest GT among the first
// num_person[b] GT slots, emit [xyz, proposal2gt, conf, bbox(2)] -> [B,P,7].
//
// R2: GT staged as float4 (xyz + pad) -> one ds_read_b128 per GT instead of
// 3x ds_read_b32; trip count padded to multiple of 4 with 1e30 sentinels
// (distance overflows to +inf, never selected; np>=1 so a real GT always
// wins) -> manual unroll-4 with a (d,idx) tree merge. Strict-< comparisons
// keep jnp.argmin's first-occurrence semantics at every merge level.

#define BB 256
#define PP 1024
#define GG 128

__global__ __launch_bounds__(256) void proposal_layer_kernel(
    const float* __restrict__ topk_index,   // [B,P,3]
    const float* __restrict__ topk_confs,   // [B,P]
    const float* __restrict__ bbox_preds,   // [B,P,2]
    const float* __restrict__ gt_3d,        // [B,G,3]
    const float* __restrict__ gt_bbox,      // [B,G,2]
    const int*   __restrict__ num_person,   // [B]
    float* __restrict__ out)                // [B,P,7]
{
    __shared__ float4 s_gt[GG];      // 2048 B: xyz + pad, sentinel beyond np
    __shared__ float  s_bb[GG * 2];  // 1024 B

    const int blocks_per_b = PP / 256;          // 4
    const int b     = blockIdx.x / blocks_per_b;
    const int ptile = blockIdx.x % blocks_per_b;
    const int p     = ptile * 256 + threadIdx.x;
    const int t     = threadIdx.x;

    const int np_b = num_person[b];             // scalar broadcast, 1..128

    // Stage GT data. Thread t < 128 owns s_gt[t]; beyond np -> sentinel so
    // the padded unroll-4 loop never selects it (d -> +inf).
    if (t < GG) {
        float4 v;
        if (t < np_b) {
            const float* g3 = gt_3d + ((size_t)b * GG + t) * 3;
            v.x = g3[0]; v.y = g3[1]; v.z = g3[2]; v.w = 0.0f;
        } else {
            v.x = 1.0e30f; v.y = 1.0e30f; v.z = 1.0e30f; v.w = 0.0f;
        }
        s_gt[t] = v;
    }
    s_bb[t] = gt_bbox[(size_t)b * (GG * 2) + t];   // 256 floats exactly
    __syncthreads();

    const size_t bp = (size_t)b * PP + p;
    const float x = topk_index[bp * 3 + 0];
    const float y = topk_index[bp * 3 + 1];
    const float z = topk_index[bp * 3 + 2];

    float best = 3.402823466e+38f;
    int   bidx = 0;
    const int np4 = (np_b + 3) & ~3;
    for (int g = 0; g < np4; g += 4) {
        const float4 g0 = s_gt[g + 0];
        const float4 g1 = s_gt[g + 1];
        const float4 g2 = s_gt[g + 2];
        const float4 g3 = s_gt[g + 3];

        const float dx0 = x - g0.x, dy0 = y - g0.y, dz0 = z - g0.z;
        const float dx1 = x - g1.x, dy1 = y - g1.y, dz1 = z - g1.z;
        const float dx2 = x - g2.x, dy2 = y - g2.y, dz2 = z - g2.z;
        const float dx3 = x - g3.x, dy3 = y - g3.y, dz3 = z - g3.z;

        const float d0 = dx0 * dx0 + dy0 * dy0 + dz0 * dz0;
        const float d1 = dx1 * dx1 + dy1 * dy1 + dz1 * dz1;
        const float d2 = dx2 * dx2 + dy2 * dy2 + dz2 * dz2;
        const float d3 = dx3 * dx3 + dy3 * dy3 + dz3 * dz3;

        // first-occurrence tie-break: strict < prefers the lower index
        const float m01 = (d1 < d0) ? d1 : d0;
        const int   i01 = (d1 < d0) ? g + 1 : g + 0;
        const float m23 = (d3 < d2) ? d3 : d2;
        const int   i23 = (d3 < d2) ? g + 3 : g + 2;
        const float m   = (m23 < m01) ? m23 : m01;
        const int   im  = (m23 < m01) ? i23 : i01;
        if (m < best) { best = m; bidx = im; }
    }

    // sqrt(best) > 500  <=>  best > 500^2 (both non-negative)
    const float p2g = (best > 500.0f * 500.0f) ? -1.0f : (float)bidx;

    // matched bbox gathered with min_gt unconditionally (matches reference)
    const float mb0 = s_bb[bidx * 2 + 0];
    const float mb1 = s_bb[bidx * 2 + 1];
    const float bp0 = bbox_preds[bp * 2 + 0];
    const float bp1 = bbox_preds[bp * 2 + 1];
    const bool cond = (p2g >= 0.0f) &&
                      ((bp0 < mb0 - 0.1f) || (bp1 < mb1 - 0.1f));
    const float o5 = cond ? mb0 : bp0;
    const float o6 = cond ? mb1 : bp1;

    const float conf = topk_confs[bp];

    float* o = out + bp * 7;
    o[0] = x;
    o[1] = y;
    o[2] = z;
    o[3] = p2g;
    o[4] = conf;
    o[5] = o5;
    o[6] = o6;
}

extern "C" void kernel_launch(void* const* d_in, const int* in_sizes, int n_in,
                              void* d_out, int out_size, void* d_ws, size_t ws_size,
                              hipStream_t stream) {
    const float* topk_index       = (const float*)d_in[0];
    const float* topk_confs       = (const float*)d_in[1];
    const float* match_bbox_preds = (const float*)d_in[2];
    const float* gt_3d            = (const float*)d_in[3];
    const float* gt_bbox          = (const float*)d_in[4];
    const int*   num_person       = (const int*)d_in[5];
    float* out = (float*)d_out;

    const int grid = BB * (PP / 256);   // 1024 blocks
    proposal_layer_kernel<<<grid, 256, 0, stream>>>(
        topk_index, topk_confs, match_bbox_preds, gt_3d, gt_bbox,
        num_person, out);
}